// Round 8
// baseline (1831.641 us; speedup 1.0000x reference)
//
#include <hip/hip_runtime.h>
#include <math.h>

// ---------------------------------------------------------------------------
// STaRNet forward, fully fused fp32 pipeline.
//
//  k_prep : fold spatial convs+BN+wf-conv+BN into M(50x22)+biasf(50);
//           fold temporal BN into COMPACT conv taps wtf[50][336] + bt[450].
//  k_main : per (batch, 256-t tile): xf tile in LDS, per-thread t:
//           h[450] on the fly -> y[64] = W^T h (v4f weight loads);
//           sum(h^2) partials.
//  k_eig  : per batch, 1024 threads: syrk y y^T (transposed staging, b128);
//           ONE-SIDED Jacobi entirely in wave 0's REGISTERS: lane L owns
//           column L (64 VGPR), partner exchange via 64 shfl (bpermute,
//           permutation -> conflict-free), gamma computed redundantly and
//           bitwise-identically on both lanes of a pair, branchless
//           sign-tricked rotation, tracked norms, NO barriers, NO LDS in
//           the round loop; lambda=||g||, v=g/lambda -> log recon -> FC.
// ---------------------------------------------------------------------------

typedef __attribute__((ext_vector_type(4))) float v4f;

#define MAXSWEEP 12
#define JTOL     1e-6f

// ws float offsets
#define WS_M      0         // 50*22
#define WS_BIASF  1100      // 50
#define WS_WTF    1152      // 50*336 compact taps
#define WS_BT     17952     // 450
#define WS_HPART  18432     // 512
#define WS_Y      32768     // 128*64*1001

__global__ void k_prep(
    const float* __restrict__ ws0, const float* __restrict__ ws1, const float* __restrict__ ws2,
    const float* __restrict__ bsg, const float* __restrict__ bsb, const float* __restrict__ bsm, const float* __restrict__ bsv,
    const float* __restrict__ wf,
    const float* __restrict__ bfg, const float* __restrict__ bfb, const float* __restrict__ bfm, const float* __restrict__ bfv,
    const float* __restrict__ wt0, const float* __restrict__ wt1, const float* __restrict__ wt2,
    const float* __restrict__ btg, const float* __restrict__ btb, const float* __restrict__ btm, const float* __restrict__ btv,
    float* __restrict__ wsf)
{
    int tid = threadIdx.x;
    if (tid < 450) {
        int c = tid;
        int i = c / 150, o = c % 150;
        int g = o / 3,   jr = o % 3;
        int k = (i == 0) ? 64 : ((i == 1) ? 32 : 16);
        float ga = btg[i*150 + o], bb = btb[i*150 + o];
        float mm = btm[i*150 + o], vv = btv[i*150 + o];
        float s = ga * rsqrtf(vv + 1e-5f);
        wsf[WS_BT + c] = bb - s * mm;
        int base = g*336 + ((i == 0) ? jr*64 : (i == 1) ? 192 + jr*32 : 288 + jr*16);
        const float* wsrc = (i == 0) ? wt0 : ((i == 1) ? wt1 : wt2);
        float* dst = wsf + WS_WTF + base;
        for (int t = 0; t < k; ++t) dst[t] = s * wsrc[o*k + t];
    }
    if (tid < 50) {
        int f = tid;
        float sf = bfg[f] * rsqrtf(bfv[f] + 1e-5f);
        float row[22];
        for (int c = 0; c < 22; ++c) row[c] = 0.f;
        float bacc = 0.f;
        for (int j = 0; j < 60; ++j) {
            int i, k, j0; const float* wsp;
            if (j < 22)      { i = 0; k = 1; j0 = j;      wsp = ws0; }
            else if (j < 42) { i = 1; k = 3; j0 = j - 22; wsp = ws1; }
            else             { i = 2; k = 5; j0 = j - 42; wsp = ws2; }
            float si = bsg[i] * rsqrtf(bsv[i] + 1e-5f);
            float bi = bsb[i] - si * bsm[i];
            float wfj = wf[f*60 + j];
            for (int d = 0; d < k; ++d) row[j0 + d] += wfj * si * wsp[d];
            bacc += wfj * bi;
        }
        for (int c = 0; c < 22; ++c) wsf[WS_M + f*22 + c] = sf * row[c];
        wsf[WS_BIASF + f] = sf * (bacc - bfm[f]) + bfb[f];
    }
}

// ---------------------------------------------------------------------------
__global__ __launch_bounds__(256) void k_main(
    const float* __restrict__ x, const float* __restrict__ wsf,
    const float* __restrict__ Wmap, float* __restrict__ y,
    float* __restrict__ hpart)
{
    const int b    = blockIdx.x >> 2;
    const int tile = blockIdx.x & 3;
    const int t0   = tile * 256;
    const int tid  = threadIdx.x;

    __shared__ float xt[50][320];   // xf tile, zero-padded (62.5 KB)
    __shared__ float wred[4];

    const float* Mg    = wsf + WS_M;
    const float* biasf = wsf + WS_BIASF;
    const float* wtf   = wsf + WS_WTF;
    const float* bt    = wsf + WS_BT;

    for (int col = tid; col < 320; col += 256) {
        int tx = t0 + col - 32;
        if (tx >= 0 && tx < 1000) {
            float xv[22];
            #pragma unroll
            for (int c = 0; c < 22; ++c) xv[c] = x[(b*22 + c)*1000 + tx];
            for (int g = 0; g < 50; ++g) {
                float a = biasf[g];
                #pragma unroll
                for (int c = 0; c < 22; ++c) a += Mg[g*22 + c] * xv[c];
                xt[g][col] = a;
            }
        } else {
            for (int g = 0; g < 50; ++g) xt[g][col] = 0.f;
        }
    }
    __syncthreads();

    const int t = t0 + tid;
    const bool act = (t <= 1000);
    v4f yv4[16];
    #pragma unroll
    for (int m = 0; m < 16; ++m) yv4[m] = (v4f){0.f, 0.f, 0.f, 0.f};
    float hsq = 0.f;

    if (act) {
        for (int g = 0; g < 50; ++g) {
            const float* xb = &xt[g][tid];
            const float* wg = wtf + g * 336;   // compact: [0..191]=b0, [192..287]=b1, [288..335]=b2
            v4f h4[9];
            #pragma unroll
            for (int j = 0; j < 9; ++j) h4[j] = (v4f){0.f, 0.f, 0.f, 0.f};
            #pragma unroll
            for (int tau = 0; tau < 64; tau += 4) {
                v4f xv = (v4f){xb[tau], xb[tau+1], xb[tau+2], xb[tau+3]};
                h4[0] += (*(const v4f*)(wg + tau))       * xv;
                h4[1] += (*(const v4f*)(wg + 64 + tau))  * xv;
                h4[2] += (*(const v4f*)(wg + 128 + tau)) * xv;
                if (tau >= 16 && tau < 48) {
                    int u = tau - 16;
                    h4[3] += (*(const v4f*)(wg + 192 + u)) * xv;
                    h4[4] += (*(const v4f*)(wg + 224 + u)) * xv;
                    h4[5] += (*(const v4f*)(wg + 256 + u)) * xv;
                }
                if (tau >= 24 && tau < 40) {
                    int u = tau - 24;
                    h4[6] += (*(const v4f*)(wg + 288 + u)) * xv;
                    h4[7] += (*(const v4f*)(wg + 304 + u)) * xv;
                    h4[8] += (*(const v4f*)(wg + 320 + u)) * xv;
                }
            }
            #pragma unroll
            for (int j = 0; j < 9; ++j) {
                int c = (j < 3) ? (3*g + j)
                      : (j < 6) ? (150 + 3*g + (j - 3))
                                : (300 + 3*g + (j - 6));
                float hv = (h4[j].x + h4[j].y) + (h4[j].z + h4[j].w) + bt[c];
                hsq += hv * hv;
                const v4f* wr4 = (const v4f*)(Wmap + c * 64);  // wave-uniform
                v4f hv4 = (v4f){hv, hv, hv, hv};
                #pragma unroll
                for (int m = 0; m < 16; ++m) yv4[m] += wr4[m] * hv4;
            }
        }
        #pragma unroll
        for (int k = 0; k < 16; ++k) {
            y[(b*64 + 4*k)*1001 + t]     = yv4[k].x;
            y[(b*64 + 4*k + 1)*1001 + t] = yv4[k].y;
            y[(b*64 + 4*k + 2)*1001 + t] = yv4[k].z;
            y[(b*64 + 4*k + 3)*1001 + t] = yv4[k].w;
        }
    }

    for (int off = 32; off > 0; off >>= 1) hsq += __shfl_down(hsq, off, 64);
    int wid = tid >> 6, lane = tid & 63;
    if (lane == 0) wred[wid] = hsq;
    __syncthreads();
    if (tid == 0) hpart[blockIdx.x] = wred[0] + wred[1] + wred[2] + wred[3];
}

// ---------------------------------------------------------------------------
union SMu {
    float ytT[128][68];   // syrk staging, transposed (34816 B)
    float G[64][68];      // G[k][i] = element i of column k (17408 B)
};

__global__ __launch_bounds__(1024) void k_eig(
    const float* __restrict__ y, const float* __restrict__ hpart,
    const float* __restrict__ fcw, const float* __restrict__ fcb,
    float* __restrict__ out)
{
    const int b    = blockIdx.x;
    const int tid  = threadIdx.x;
    const int w    = tid >> 6;     // wave 0..15
    const int lane = tid & 63;

    __shared__ SMu U;
    __shared__ float le[64];
    __shared__ float wred2[16];

    // ---- syrk: acc = y y^T; transposed staging, b128 MAC on 256 thr ----
    const int mg = tid >> 4, ng = tid & 15;       // valid for tid<256
    const int m0 = mg * 4,  n0 = ng * 4;
    float acc[16];
    #pragma unroll
    for (int i = 0; i < 16; ++i) acc[i] = 0.f;
    for (int tile = 0; tile < 8; ++tile) {
        #pragma unroll
        for (int k = 0; k < 8; ++k) {
            int idx = tid + k*1024;
            int col = idx >> 7, row = idx & 127;   // col=m, row=t-in-tile
            int tg = tile * 128 + row;
            U.ytT[row][col] = (tg <= 1000) ? y[(b*64 + col)*1001 + tg] : 0.f;
        }
        __syncthreads();
        if (tid < 256) {
            for (int tt = 0; tt < 128; ++tt) {
                v4f ym = *(const v4f*)&U.ytT[tt][m0];
                v4f yn = *(const v4f*)&U.ytT[tt][n0];
                #pragma unroll
                for (int i = 0; i < 4; ++i)
                    #pragma unroll
                    for (int j = 0; j < 4; ++j) acc[i*4 + j] += ym[i] * yn[j];
            }
        }
        __syncthreads();
    }
    if (tid < 256) {
        float hs = hpart[b*4] + hpart[b*4+1] + hpart[b*4+2] + hpart[b*4+3];
        float mu = hs / (999.f * 450.f);
        #pragma unroll
        for (int i = 0; i < 4; ++i)
            #pragma unroll
            for (int j = 0; j < 4; ++j) {
                int mm = m0 + i, nn = n0 + j;
                U.G[mm][nn] = acc[i*4 + j] * (0.95f / 999.f)
                            + ((mm == nn) ? 0.05f * mu : 0.f);
            }
    }
    __syncthreads();

    // ---- one-sided cyclic Jacobi, single wave, registers only ----
    // Lane L owns column L: g[i] = G[L][i].  Round rr pairs:
    //   (63, rr) and ((rr+j)%63, (rr+63-j)%63) for j=1..31.
    //   partner(L) = rr if L==63; 63 if L==rr; else (2rr-L) mod 63.
    //   role p (sgn=+1) iff L==63 or 1 <= (L-rr) mod 63 <= 31.
    // gamma = sum_i g_own[i]*g_recv[i]: identical product sequence on both
    // lanes of a pair -> bitwise-equal decisions, no reduction needed.
    // Rotation branchless: g' = c*g + se*gq, se = -sgn*s; nr' = nr - sgn*t*gam.
    if (w == 0) {
        float g[64];
        #pragma unroll
        for (int i = 0; i < 16; ++i) {
            v4f t4 = *(const v4f*)&U.G[lane][4*i];
            g[4*i] = t4.x; g[4*i+1] = t4.y; g[4*i+2] = t4.z; g[4*i+3] = t4.w;
        }
        float nr;
        {
            float s0 = 0.f, s1 = 0.f, s2 = 0.f, s3 = 0.f;
            #pragma unroll
            for (int i = 0; i < 64; i += 4) {
                s0 += g[i]*g[i];     s1 += g[i+1]*g[i+1];
                s2 += g[i+2]*g[i+2]; s3 += g[i+3]*g[i+3];
            }
            nr = (s0 + s1) + (s2 + s3);
        }

        for (int sweep = 0; sweep < MAXSWEEP; ++sweep) {
            int allc = 1;
            for (int rr = 0; rr < 63; ++rr) {
                int partner, sgn;
                if (lane == 63) { partner = rr; sgn = 1; }
                else {
                    int d = lane - rr; if (d < 0) d += 63;
                    if (d == 0) { partner = 63; sgn = -1; }
                    else {
                        int pp = 2*rr - lane;
                        if (pp < 0)   pp += 63;
                        if (pp < 0)   pp += 63;
                        if (pp >= 63) pp -= 63;
                        partner = pp;
                        sgn = (d <= 31) ? 1 : -1;
                    }
                }
                float gq[64];
                #pragma unroll
                for (int i = 0; i < 64; ++i) gq[i] = __shfl(g[i], partner, 64);
                float nq = __shfl(nr, partner, 64);

                float s0 = 0.f, s1 = 0.f, s2 = 0.f, s3 = 0.f;
                #pragma unroll
                for (int i = 0; i < 64; i += 4) {
                    s0 += g[i]*gq[i];     s1 += g[i+1]*gq[i+1];
                    s2 += g[i+2]*gq[i+2]; s3 += g[i+3]*gq[i+3];
                }
                float gam = (s0 + s1) + (s2 + s3);

                if (fabsf(gam) > JTOL * sqrtf(nr * nq)) {
                    allc = 0;
                    float diff = (sgn > 0) ? (nq - nr) : (nr - nq);  // be - al
                    float tau = diff * __builtin_amdgcn_rcpf(2.f * gam);
                    float t  = copysignf(1.f, tau) / (fabsf(tau) + sqrtf(1.f + tau*tau));
                    float c  = rsqrtf(1.f + t*t);
                    float s  = t * c;
                    float se = (sgn > 0) ? -s : s;
                    #pragma unroll
                    for (int i = 0; i < 64; ++i) g[i] = c*g[i] + se*gq[i];
                    nr -= (sgn > 0) ? t*gam : -t*gam;
                }
            }
            if (__all(allc)) break;
        }

        // write back column + le[k] = log(lambda)/lambda^2 with fresh norm
        #pragma unroll
        for (int i = 0; i < 16; ++i) {
            v4f t4 = (v4f){g[4*i], g[4*i+1], g[4*i+2], g[4*i+3]};
            *(v4f*)&U.G[lane][4*i] = t4;
        }
        {
            float s0 = 0.f, s1 = 0.f, s2 = 0.f, s3 = 0.f;
            #pragma unroll
            for (int i = 0; i < 64; i += 4) {
                s0 += g[i]*g[i];     s1 += g[i+1]*g[i+1];
                s2 += g[i+2]*g[i+2]; s3 += g[i+3]*g[i+3];
            }
            float n2 = fmaxf((s0 + s1) + (s2 + s3), 1e-12f);
            le[lane] = 0.5f * logf(n2) / n2;   // log(sqrt(n2)) / n2
        }
    }
    __syncthreads();

    // ---- log-eig reconstruction + FC (first 256 threads) ----
    // log_mapped = sum_k le[k] * g_k g_k^T   (g_k = col k of G, contiguous)
    if (tid < 256) {
        float lm[16];
        #pragma unroll
        for (int i = 0; i < 16; ++i) lm[i] = 0.f;
        for (int k = 0; k < 64; ++k) {
            float l = le[k];
            v4f gm = *(const v4f*)&U.G[k][m0];
            v4f gn = *(const v4f*)&U.G[k][n0];
            #pragma unroll
            for (int i = 0; i < 4; ++i) {
                float vm = gm[i] * l;
                #pragma unroll
                for (int j = 0; j < 4; ++j) lm[i*4 + j] += vm * gn[j];
            }
        }

        float fa[4];
        #pragma unroll
        for (int o = 0; o < 4; ++o) fa[o] = 0.f;
        #pragma unroll
        for (int i = 0; i < 4; ++i)
            #pragma unroll
            for (int j = 0; j < 4; ++j) {
                int gi = m0 + i, gj = n0 + j;
                if (gi <= gj) {
                    int p = gi*64 - (gi*(gi-1))/2 + (gj - gi);
                    float lv = lm[i*4 + j];
                    #pragma unroll
                    for (int o = 0; o < 4; ++o) fa[o] += lv * fcw[o*2080 + p];
                }
            }

        #pragma unroll
        for (int o = 0; o < 4; ++o)
            for (int off = 32; off > 0; off >>= 1)
                fa[o] += __shfl_down(fa[o], off, 64);
        if (lane == 0) {
            #pragma unroll
            for (int o = 0; o < 4; ++o) wred2[w*4 + o] = fa[o];
        }
    }
    __syncthreads();
    if (tid < 4)
        out[b*4 + tid] = wred2[tid] + wred2[4 + tid] + wred2[8 + tid]
                       + wred2[12 + tid] + fcb[tid];
}

// ---------------------------------------------------------------------------
extern "C" void kernel_launch(void* const* d_in, const int* in_sizes, int n_in,
                              void* d_out, int out_size, void* d_ws, size_t ws_size,
                              hipStream_t stream) {
    (void)in_sizes; (void)n_in; (void)out_size; (void)ws_size;
    const float* x   = (const float*)d_in[0];
    const float* ws0 = (const float*)d_in[1];
    const float* ws1 = (const float*)d_in[2];
    const float* ws2 = (const float*)d_in[3];
    const float* bsg = (const float*)d_in[4];
    const float* bsb = (const float*)d_in[5];
    const float* bsm = (const float*)d_in[6];
    const float* bsv = (const float*)d_in[7];
    const float* wf  = (const float*)d_in[8];
    const float* bfg = (const float*)d_in[9];
    const float* bfb = (const float*)d_in[10];
    const float* bfm = (const float*)d_in[11];
    const float* bfv = (const float*)d_in[12];
    const float* wt0 = (const float*)d_in[13];
    const float* wt1 = (const float*)d_in[14];
    const float* wt2 = (const float*)d_in[15];
    const float* btg = (const float*)d_in[16];
    const float* btb = (const float*)d_in[17];
    const float* btm = (const float*)d_in[18];
    const float* btv = (const float*)d_in[19];
    const float* Wm  = (const float*)d_in[20];
    const float* fcw = (const float*)d_in[21];
    const float* fcb = (const float*)d_in[22];

    float* wsf   = (float*)d_ws;
    float* yb    = wsf + WS_Y;
    float* hpart = wsf + WS_HPART;

    k_prep<<<1, 512, 0, stream>>>(ws0, ws1, ws2, bsg, bsb, bsm, bsv,
                                  wf, bfg, bfb, bfm, bfv,
                                  wt0, wt1, wt2, btg, btb, btm, btv, wsf);
    k_main<<<512, 256, 0, stream>>>(x, wsf, Wm, yb, hpart);
    k_eig<<<128, 1024, 0, stream>>>(yb, hpart, fcw, fcb, (float*)d_out);
}

// Round 9
// 1041.825 us; speedup vs baseline: 1.7581x; 1.7581x over previous
//
#include <hip/hip_runtime.h>
#include <math.h>

// ---------------------------------------------------------------------------
// STaRNet forward, fully fused fp32 pipeline.
//
//  k_prep : fold spatial convs+BN+wf-conv+BN into M(50x22)+biasf(50);
//           fold temporal BN into COMPACT conv taps wtf[50][336] + bt[450].
//  k_main : per (batch, 256-t tile): xf tile in LDS, per-thread t:
//           h[450] on the fly -> y[64] = W^T h (v4f weight loads);
//           sum(h^2) partials.
//  k_eig  : per batch, 256 threads, __launch_bounds__(256,1) so the
//           register-resident Jacobi gets a full VGPR budget (R8 lesson:
//           1024-thread launch bounds capped VGPRs at 64 -> scratch spill).
//           syrk y y^T (transposed staging, b128); ONE-SIDED Jacobi in wave
//           0's registers: lane L owns column L (64 VGPR), partner exchange
//           via 64 shfl, gamma computed redundantly bitwise-identically on
//           both lanes of a pair, branchless rotation, tracked norms, no
//           barriers/LDS in the round loop; lambda=||g||, v=g/lambda ->
//           log recon -> FC.
// ---------------------------------------------------------------------------

typedef __attribute__((ext_vector_type(4))) float v4f;

#define MAXSWEEP 12
#define JTOL     1e-6f

// ws float offsets
#define WS_M      0         // 50*22
#define WS_BIASF  1100      // 50
#define WS_WTF    1152      // 50*336 compact taps
#define WS_BT     17952     // 450
#define WS_HPART  18432     // 512
#define WS_Y      32768     // 128*64*1001

__global__ void k_prep(
    const float* __restrict__ ws0, const float* __restrict__ ws1, const float* __restrict__ ws2,
    const float* __restrict__ bsg, const float* __restrict__ bsb, const float* __restrict__ bsm, const float* __restrict__ bsv,
    const float* __restrict__ wf,
    const float* __restrict__ bfg, const float* __restrict__ bfb, const float* __restrict__ bfm, const float* __restrict__ bfv,
    const float* __restrict__ wt0, const float* __restrict__ wt1, const float* __restrict__ wt2,
    const float* __restrict__ btg, const float* __restrict__ btb, const float* __restrict__ btm, const float* __restrict__ btv,
    float* __restrict__ wsf)
{
    int tid = threadIdx.x;
    if (tid < 450) {
        int c = tid;
        int i = c / 150, o = c % 150;
        int g = o / 3,   jr = o % 3;
        int k = (i == 0) ? 64 : ((i == 1) ? 32 : 16);
        float ga = btg[i*150 + o], bb = btb[i*150 + o];
        float mm = btm[i*150 + o], vv = btv[i*150 + o];
        float s = ga * rsqrtf(vv + 1e-5f);
        wsf[WS_BT + c] = bb - s * mm;
        int base = g*336 + ((i == 0) ? jr*64 : (i == 1) ? 192 + jr*32 : 288 + jr*16);
        const float* wsrc = (i == 0) ? wt0 : ((i == 1) ? wt1 : wt2);
        float* dst = wsf + WS_WTF + base;
        for (int t = 0; t < k; ++t) dst[t] = s * wsrc[o*k + t];
    }
    if (tid < 50) {
        int f = tid;
        float sf = bfg[f] * rsqrtf(bfv[f] + 1e-5f);
        float row[22];
        for (int c = 0; c < 22; ++c) row[c] = 0.f;
        float bacc = 0.f;
        for (int j = 0; j < 60; ++j) {
            int i, k, j0; const float* wsp;
            if (j < 22)      { i = 0; k = 1; j0 = j;      wsp = ws0; }
            else if (j < 42) { i = 1; k = 3; j0 = j - 22; wsp = ws1; }
            else             { i = 2; k = 5; j0 = j - 42; wsp = ws2; }
            float si = bsg[i] * rsqrtf(bsv[i] + 1e-5f);
            float bi = bsb[i] - si * bsm[i];
            float wfj = wf[f*60 + j];
            for (int d = 0; d < k; ++d) row[j0 + d] += wfj * si * wsp[d];
            bacc += wfj * bi;
        }
        for (int c = 0; c < 22; ++c) wsf[WS_M + f*22 + c] = sf * row[c];
        wsf[WS_BIASF + f] = sf * (bacc - bfm[f]) + bfb[f];
    }
}

// ---------------------------------------------------------------------------
__global__ __launch_bounds__(256) void k_main(
    const float* __restrict__ x, const float* __restrict__ wsf,
    const float* __restrict__ Wmap, float* __restrict__ y,
    float* __restrict__ hpart)
{
    const int b    = blockIdx.x >> 2;
    const int tile = blockIdx.x & 3;
    const int t0   = tile * 256;
    const int tid  = threadIdx.x;

    __shared__ float xt[50][320];   // xf tile, zero-padded (62.5 KB)
    __shared__ float wred[4];

    const float* Mg    = wsf + WS_M;
    const float* biasf = wsf + WS_BIASF;
    const float* wtf   = wsf + WS_WTF;
    const float* bt    = wsf + WS_BT;

    for (int col = tid; col < 320; col += 256) {
        int tx = t0 + col - 32;
        if (tx >= 0 && tx < 1000) {
            float xv[22];
            #pragma unroll
            for (int c = 0; c < 22; ++c) xv[c] = x[(b*22 + c)*1000 + tx];
            for (int g = 0; g < 50; ++g) {
                float a = biasf[g];
                #pragma unroll
                for (int c = 0; c < 22; ++c) a += Mg[g*22 + c] * xv[c];
                xt[g][col] = a;
            }
        } else {
            for (int g = 0; g < 50; ++g) xt[g][col] = 0.f;
        }
    }
    __syncthreads();

    const int t = t0 + tid;
    const bool act = (t <= 1000);
    v4f yv4[16];
    #pragma unroll
    for (int m = 0; m < 16; ++m) yv4[m] = (v4f){0.f, 0.f, 0.f, 0.f};
    float hsq = 0.f;

    if (act) {
        for (int g = 0; g < 50; ++g) {
            const float* xb = &xt[g][tid];
            const float* wg = wtf + g * 336;   // compact: [0..191]=b0, [192..287]=b1, [288..335]=b2
            v4f h4[9];
            #pragma unroll
            for (int j = 0; j < 9; ++j) h4[j] = (v4f){0.f, 0.f, 0.f, 0.f};
            #pragma unroll
            for (int tau = 0; tau < 64; tau += 4) {
                v4f xv = (v4f){xb[tau], xb[tau+1], xb[tau+2], xb[tau+3]};
                h4[0] += (*(const v4f*)(wg + tau))       * xv;
                h4[1] += (*(const v4f*)(wg + 64 + tau))  * xv;
                h4[2] += (*(const v4f*)(wg + 128 + tau)) * xv;
                if (tau >= 16 && tau < 48) {
                    int u = tau - 16;
                    h4[3] += (*(const v4f*)(wg + 192 + u)) * xv;
                    h4[4] += (*(const v4f*)(wg + 224 + u)) * xv;
                    h4[5] += (*(const v4f*)(wg + 256 + u)) * xv;
                }
                if (tau >= 24 && tau < 40) {
                    int u = tau - 24;
                    h4[6] += (*(const v4f*)(wg + 288 + u)) * xv;
                    h4[7] += (*(const v4f*)(wg + 304 + u)) * xv;
                    h4[8] += (*(const v4f*)(wg + 320 + u)) * xv;
                }
            }
            #pragma unroll
            for (int j = 0; j < 9; ++j) {
                int c = (j < 3) ? (3*g + j)
                      : (j < 6) ? (150 + 3*g + (j - 3))
                                : (300 + 3*g + (j - 6));
                float hv = (h4[j].x + h4[j].y) + (h4[j].z + h4[j].w) + bt[c];
                hsq += hv * hv;
                const v4f* wr4 = (const v4f*)(Wmap + c * 64);  // wave-uniform
                v4f hv4 = (v4f){hv, hv, hv, hv};
                #pragma unroll
                for (int m = 0; m < 16; ++m) yv4[m] += wr4[m] * hv4;
            }
        }
        #pragma unroll
        for (int k = 0; k < 16; ++k) {
            y[(b*64 + 4*k)*1001 + t]     = yv4[k].x;
            y[(b*64 + 4*k + 1)*1001 + t] = yv4[k].y;
            y[(b*64 + 4*k + 2)*1001 + t] = yv4[k].z;
            y[(b*64 + 4*k + 3)*1001 + t] = yv4[k].w;
        }
    }

    for (int off = 32; off > 0; off >>= 1) hsq += __shfl_down(hsq, off, 64);
    int wid = tid >> 6, lane = tid & 63;
    if (lane == 0) wred[wid] = hsq;
    __syncthreads();
    if (tid == 0) hpart[blockIdx.x] = wred[0] + wred[1] + wred[2] + wred[3];
}

// ---------------------------------------------------------------------------
union SMu {
    float ytT[128][68];   // syrk staging, transposed (34816 B)
    float G[64][68];      // G[k][i] = element i of column k (17408 B)
};

__global__ __launch_bounds__(256, 1) void k_eig(
    const float* __restrict__ y, const float* __restrict__ hpart,
    const float* __restrict__ fcw, const float* __restrict__ fcb,
    float* __restrict__ out)
{
    const int b    = blockIdx.x;
    const int tid  = threadIdx.x;
    const int w    = tid >> 6;     // wave 0..3
    const int lane = tid & 63;

    __shared__ SMu U;
    __shared__ float le[64];
    __shared__ float wred2[16];

    // ---- syrk: acc = y y^T; transposed staging, b128 MAC, 256 thr ----
    const int mg = tid >> 4, ng = tid & 15;
    const int m0 = mg * 4,  n0 = ng * 4;
    float acc[16];
    #pragma unroll
    for (int i = 0; i < 16; ++i) acc[i] = 0.f;
    for (int tile = 0; tile < 8; ++tile) {
        #pragma unroll
        for (int k = 0; k < 32; ++k) {
            int idx = tid + k*256;
            int col = idx >> 7, row = idx & 127;   // col=m, row=t-in-tile
            int tg = tile * 128 + row;
            U.ytT[row][col] = (tg <= 1000) ? y[(b*64 + col)*1001 + tg] : 0.f;
        }
        __syncthreads();
        for (int tt = 0; tt < 128; ++tt) {
            v4f ym = *(const v4f*)&U.ytT[tt][m0];
            v4f yn = *(const v4f*)&U.ytT[tt][n0];
            #pragma unroll
            for (int i = 0; i < 4; ++i)
                #pragma unroll
                for (int j = 0; j < 4; ++j) acc[i*4 + j] += ym[i] * yn[j];
        }
        __syncthreads();
    }
    {
        float hs = hpart[b*4] + hpart[b*4+1] + hpart[b*4+2] + hpart[b*4+3];
        float mu = hs / (999.f * 450.f);
        #pragma unroll
        for (int i = 0; i < 4; ++i)
            #pragma unroll
            for (int j = 0; j < 4; ++j) {
                int mm = m0 + i, nn = n0 + j;
                U.G[mm][nn] = acc[i*4 + j] * (0.95f / 999.f)
                            + ((mm == nn) ? 0.05f * mu : 0.f);
            }
    }
    __syncthreads();

    // ---- one-sided cyclic Jacobi, single wave, registers only ----
    // Lane L owns column L: g[i] = G[L][i].  Round rr pairs:
    //   (63, rr) and ((rr+j)%63, (rr+63-j)%63) for j=1..31.
    //   partner(L) = rr if L==63; 63 if L==rr; else (2rr-L) mod 63.
    //   role p (sgn=+1) iff L==63 or 1 <= (L-rr) mod 63 <= 31.
    // gamma = sum_i g_own[i]*g_recv[i]: identical product sequence on both
    // lanes of a pair -> bitwise-equal decisions, no reduction needed.
    // Rotation branchless: g' = c*g + se*gq, se = -sgn*s; nr' = nr - sgn*t*gam.
    if (w == 0) {
        float g[64];
        #pragma unroll
        for (int i = 0; i < 16; ++i) {
            v4f t4 = *(const v4f*)&U.G[lane][4*i];
            g[4*i] = t4.x; g[4*i+1] = t4.y; g[4*i+2] = t4.z; g[4*i+3] = t4.w;
        }
        float nr;
        {
            float s0 = 0.f, s1 = 0.f, s2 = 0.f, s3 = 0.f;
            #pragma unroll
            for (int i = 0; i < 64; i += 4) {
                s0 += g[i]*g[i];     s1 += g[i+1]*g[i+1];
                s2 += g[i+2]*g[i+2]; s3 += g[i+3]*g[i+3];
            }
            nr = (s0 + s1) + (s2 + s3);
        }

        for (int sweep = 0; sweep < MAXSWEEP; ++sweep) {
            int allc = 1;
            for (int rr = 0; rr < 63; ++rr) {
                int partner, sgn;
                if (lane == 63) { partner = rr; sgn = 1; }
                else {
                    int d = lane - rr; if (d < 0) d += 63;
                    if (d == 0) { partner = 63; sgn = -1; }
                    else {
                        int pp = 2*rr - lane;
                        if (pp < 0)   pp += 63;
                        if (pp < 0)   pp += 63;
                        if (pp >= 63) pp -= 63;
                        partner = pp;
                        sgn = (d <= 31) ? 1 : -1;
                    }
                }
                float gq[64];
                #pragma unroll
                for (int i = 0; i < 64; ++i) gq[i] = __shfl(g[i], partner, 64);
                float nq = __shfl(nr, partner, 64);

                float s0 = 0.f, s1 = 0.f, s2 = 0.f, s3 = 0.f;
                #pragma unroll
                for (int i = 0; i < 64; i += 4) {
                    s0 += g[i]*gq[i];     s1 += g[i+1]*gq[i+1];
                    s2 += g[i+2]*gq[i+2]; s3 += g[i+3]*gq[i+3];
                }
                float gam = (s0 + s1) + (s2 + s3);

                if (fabsf(gam) > JTOL * sqrtf(nr * nq)) {
                    allc = 0;
                    float diff = (sgn > 0) ? (nq - nr) : (nr - nq);  // be - al
                    float tau = diff * __builtin_amdgcn_rcpf(2.f * gam);
                    float t  = copysignf(1.f, tau) / (fabsf(tau) + sqrtf(1.f + tau*tau));
                    float c  = rsqrtf(1.f + t*t);
                    float s  = t * c;
                    float se = (sgn > 0) ? -s : s;
                    #pragma unroll
                    for (int i = 0; i < 64; ++i) g[i] = c*g[i] + se*gq[i];
                    nr -= (sgn > 0) ? t*gam : -t*gam;
                }
            }
            if (__all(allc)) break;
        }

        // write back column + le[k] = log(lambda)/lambda^2 with fresh norm
        #pragma unroll
        for (int i = 0; i < 16; ++i) {
            v4f t4 = (v4f){g[4*i], g[4*i+1], g[4*i+2], g[4*i+3]};
            *(v4f*)&U.G[lane][4*i] = t4;
        }
        {
            float s0 = 0.f, s1 = 0.f, s2 = 0.f, s3 = 0.f;
            #pragma unroll
            for (int i = 0; i < 64; i += 4) {
                s0 += g[i]*g[i];     s1 += g[i+1]*g[i+1];
                s2 += g[i+2]*g[i+2]; s3 += g[i+3]*g[i+3];
            }
            float n2 = fmaxf((s0 + s1) + (s2 + s3), 1e-12f);
            le[lane] = 0.5f * logf(n2) / n2;   // log(sqrt(n2)) / n2
        }
    }
    __syncthreads();

    // ---- log-eig reconstruction + FC ----
    // log_mapped = sum_k le[k] * g_k g_k^T   (g_k = col k of G, contiguous)
    {
        float lm[16];
        #pragma unroll
        for (int i = 0; i < 16; ++i) lm[i] = 0.f;
        for (int k = 0; k < 64; ++k) {
            float l = le[k];
            v4f gm = *(const v4f*)&U.G[k][m0];
            v4f gn = *(const v4f*)&U.G[k][n0];
            #pragma unroll
            for (int i = 0; i < 4; ++i) {
                float vm = gm[i] * l;
                #pragma unroll
                for (int j = 0; j < 4; ++j) lm[i*4 + j] += vm * gn[j];
            }
        }

        float fa[4];
        #pragma unroll
        for (int o = 0; o < 4; ++o) fa[o] = 0.f;
        #pragma unroll
        for (int i = 0; i < 4; ++i)
            #pragma unroll
            for (int j = 0; j < 4; ++j) {
                int gi = m0 + i, gj = n0 + j;
                if (gi <= gj) {
                    int p = gi*64 - (gi*(gi-1))/2 + (gj - gi);
                    float lv = lm[i*4 + j];
                    #pragma unroll
                    for (int o = 0; o < 4; ++o) fa[o] += lv * fcw[o*2080 + p];
                }
            }

        #pragma unroll
        for (int o = 0; o < 4; ++o)
            for (int off = 32; off > 0; off >>= 1)
                fa[o] += __shfl_down(fa[o], off, 64);
        if (lane == 0) {
            #pragma unroll
            for (int o = 0; o < 4; ++o) wred2[w*4 + o] = fa[o];
        }
    }
    __syncthreads();
    if (tid < 4)
        out[b*4 + tid] = wred2[tid] + wred2[4 + tid] + wred2[8 + tid]
                       + wred2[12 + tid] + fcb[tid];
}

// ---------------------------------------------------------------------------
extern "C" void kernel_launch(void* const* d_in, const int* in_sizes, int n_in,
                              void* d_out, int out_size, void* d_ws, size_t ws_size,
                              hipStream_t stream) {
    (void)in_sizes; (void)n_in; (void)out_size; (void)ws_size;
    const float* x   = (const float*)d_in[0];
    const float* ws0 = (const float*)d_in[1];
    const float* ws1 = (const float*)d_in[2];
    const float* ws2 = (const float*)d_in[3];
    const float* bsg = (const float*)d_in[4];
    const float* bsb = (const float*)d_in[5];
    const float* bsm = (const float*)d_in[6];
    const float* bsv = (const float*)d_in[7];
    const float* wf  = (const float*)d_in[8];
    const float* bfg = (const float*)d_in[9];
    const float* bfb = (const float*)d_in[10];
    const float* bfm = (const float*)d_in[11];
    const float* bfv = (const float*)d_in[12];
    const float* wt0 = (const float*)d_in[13];
    const float* wt1 = (const float*)d_in[14];
    const float* wt2 = (const float*)d_in[15];
    const float* btg = (const float*)d_in[16];
    const float* btb = (const float*)d_in[17];
    const float* btm = (const float*)d_in[18];
    const float* btv = (const float*)d_in[19];
    const float* Wm  = (const float*)d_in[20];
    const float* fcw = (const float*)d_in[21];
    const float* fcb = (const float*)d_in[22];

    float* wsf   = (float*)d_ws;
    float* yb    = wsf + WS_Y;
    float* hpart = wsf + WS_HPART;

    k_prep<<<1, 512, 0, stream>>>(ws0, ws1, ws2, bsg, bsb, bsm, bsv,
                                  wf, bfg, bfb, bfm, bfv,
                                  wt0, wt1, wt2, btg, btb, btm, btv, wsf);
    k_main<<<512, 256, 0, stream>>>(x, wsf, Wm, yb, hpart);
    k_eig<<<128, 256, 0, stream>>>(yb, hpart, fcw, fcb, (float*)d_out);
}

// Round 10
// 816.161 us; speedup vs baseline: 2.2442x; 1.2765x over previous
//
#include <hip/hip_runtime.h>
#include <math.h>

// ---------------------------------------------------------------------------
// STaRNet forward, fully fused fp32 pipeline.
//
//  k_prep : fold spatial convs+BN+wf-conv+BN into M(50x22)+biasf(50);
//           fold temporal BN into COMPACT conv taps wtf[50][336] + bt[450].
//  k_main : per (batch, 256-t tile): xf tile in LDS, per-thread t:
//           h[450] on the fly -> y[64] = W^T h (v4f weight loads);
//           sum(h^2) partials.
//  k_eig  : per batch, 256 threads: syrk y y^T (transposed staging, b128);
//           ONE-SIDED Jacobi, 4-wave ROW-SPLIT (R9 lesson: single-wave had
//           no TLP, VALUBusy 5.6%): wave w, lane L holds rows [16w,16w+16)
//           of column L in 16 VGPRs.  Per round: 16 bpermute + 16-FMA
//           partial dot per wave; gamma via double-buffered LDS partials
//           (1 barrier/round); (c,s) recomputed bitwise-identically in all
//           waves (commutative products + fixed add order); rotation on own
//           rows; norms tracked in registers.  lambda=||g||, v=g/lambda ->
//           log recon -> FC.
// ---------------------------------------------------------------------------

typedef __attribute__((ext_vector_type(4))) float v4f;

#define MAXSWEEP 12
#define JTOL     1e-6f

// ws float offsets
#define WS_M      0         // 50*22
#define WS_BIASF  1100      // 50
#define WS_WTF    1152      // 50*336 compact taps
#define WS_BT     17952     // 450
#define WS_HPART  18432     // 512
#define WS_Y      32768     // 128*64*1001

__global__ void k_prep(
    const float* __restrict__ ws0, const float* __restrict__ ws1, const float* __restrict__ ws2,
    const float* __restrict__ bsg, const float* __restrict__ bsb, const float* __restrict__ bsm, const float* __restrict__ bsv,
    const float* __restrict__ wf,
    const float* __restrict__ bfg, const float* __restrict__ bfb, const float* __restrict__ bfm, const float* __restrict__ bfv,
    const float* __restrict__ wt0, const float* __restrict__ wt1, const float* __restrict__ wt2,
    const float* __restrict__ btg, const float* __restrict__ btb, const float* __restrict__ btm, const float* __restrict__ btv,
    float* __restrict__ wsf)
{
    int tid = threadIdx.x;
    if (tid < 450) {
        int c = tid;
        int i = c / 150, o = c % 150;
        int g = o / 3,   jr = o % 3;
        int k = (i == 0) ? 64 : ((i == 1) ? 32 : 16);
        float ga = btg[i*150 + o], bb = btb[i*150 + o];
        float mm = btm[i*150 + o], vv = btv[i*150 + o];
        float s = ga * rsqrtf(vv + 1e-5f);
        wsf[WS_BT + c] = bb - s * mm;
        int base = g*336 + ((i == 0) ? jr*64 : (i == 1) ? 192 + jr*32 : 288 + jr*16);
        const float* wsrc = (i == 0) ? wt0 : ((i == 1) ? wt1 : wt2);
        float* dst = wsf + WS_WTF + base;
        for (int t = 0; t < k; ++t) dst[t] = s * wsrc[o*k + t];
    }
    if (tid < 50) {
        int f = tid;
        float sf = bfg[f] * rsqrtf(bfv[f] + 1e-5f);
        float row[22];
        for (int c = 0; c < 22; ++c) row[c] = 0.f;
        float bacc = 0.f;
        for (int j = 0; j < 60; ++j) {
            int i, k, j0; const float* wsp;
            if (j < 22)      { i = 0; k = 1; j0 = j;      wsp = ws0; }
            else if (j < 42) { i = 1; k = 3; j0 = j - 22; wsp = ws1; }
            else             { i = 2; k = 5; j0 = j - 42; wsp = ws2; }
            float si = bsg[i] * rsqrtf(bsv[i] + 1e-5f);
            float bi = bsb[i] - si * bsm[i];
            float wfj = wf[f*60 + j];
            for (int d = 0; d < k; ++d) row[j0 + d] += wfj * si * wsp[d];
            bacc += wfj * bi;
        }
        for (int c = 0; c < 22; ++c) wsf[WS_M + f*22 + c] = sf * row[c];
        wsf[WS_BIASF + f] = sf * (bacc - bfm[f]) + bfb[f];
    }
}

// ---------------------------------------------------------------------------
__global__ __launch_bounds__(256) void k_main(
    const float* __restrict__ x, const float* __restrict__ wsf,
    const float* __restrict__ Wmap, float* __restrict__ y,
    float* __restrict__ hpart)
{
    const int b    = blockIdx.x >> 2;
    const int tile = blockIdx.x & 3;
    const int t0   = tile * 256;
    const int tid  = threadIdx.x;

    __shared__ float xt[50][320];   // xf tile, zero-padded (62.5 KB)
    __shared__ float wred[4];

    const float* Mg    = wsf + WS_M;
    const float* biasf = wsf + WS_BIASF;
    const float* wtf   = wsf + WS_WTF;
    const float* bt    = wsf + WS_BT;

    for (int col = tid; col < 320; col += 256) {
        int tx = t0 + col - 32;
        if (tx >= 0 && tx < 1000) {
            float xv[22];
            #pragma unroll
            for (int c = 0; c < 22; ++c) xv[c] = x[(b*22 + c)*1000 + tx];
            for (int g = 0; g < 50; ++g) {
                float a = biasf[g];
                #pragma unroll
                for (int c = 0; c < 22; ++c) a += Mg[g*22 + c] * xv[c];
                xt[g][col] = a;
            }
        } else {
            for (int g = 0; g < 50; ++g) xt[g][col] = 0.f;
        }
    }
    __syncthreads();

    const int t = t0 + tid;
    const bool act = (t <= 1000);
    v4f yv4[16];
    #pragma unroll
    for (int m = 0; m < 16; ++m) yv4[m] = (v4f){0.f, 0.f, 0.f, 0.f};
    float hsq = 0.f;

    if (act) {
        for (int g = 0; g < 50; ++g) {
            const float* xb = &xt[g][tid];
            const float* wg = wtf + g * 336;   // compact: [0..191]=b0, [192..287]=b1, [288..335]=b2
            v4f h4[9];
            #pragma unroll
            for (int j = 0; j < 9; ++j) h4[j] = (v4f){0.f, 0.f, 0.f, 0.f};
            #pragma unroll
            for (int tau = 0; tau < 64; tau += 4) {
                v4f xv = (v4f){xb[tau], xb[tau+1], xb[tau+2], xb[tau+3]};
                h4[0] += (*(const v4f*)(wg + tau))       * xv;
                h4[1] += (*(const v4f*)(wg + 64 + tau))  * xv;
                h4[2] += (*(const v4f*)(wg + 128 + tau)) * xv;
                if (tau >= 16 && tau < 48) {
                    int u = tau - 16;
                    h4[3] += (*(const v4f*)(wg + 192 + u)) * xv;
                    h4[4] += (*(const v4f*)(wg + 224 + u)) * xv;
                    h4[5] += (*(const v4f*)(wg + 256 + u)) * xv;
                }
                if (tau >= 24 && tau < 40) {
                    int u = tau - 24;
                    h4[6] += (*(const v4f*)(wg + 288 + u)) * xv;
                    h4[7] += (*(const v4f*)(wg + 304 + u)) * xv;
                    h4[8] += (*(const v4f*)(wg + 320 + u)) * xv;
                }
            }
            #pragma unroll
            for (int j = 0; j < 9; ++j) {
                int c = (j < 3) ? (3*g + j)
                      : (j < 6) ? (150 + 3*g + (j - 3))
                                : (300 + 3*g + (j - 6));
                float hv = (h4[j].x + h4[j].y) + (h4[j].z + h4[j].w) + bt[c];
                hsq += hv * hv;
                const v4f* wr4 = (const v4f*)(Wmap + c * 64);  // wave-uniform
                v4f hv4 = (v4f){hv, hv, hv, hv};
                #pragma unroll
                for (int m = 0; m < 16; ++m) yv4[m] += wr4[m] * hv4;
            }
        }
        #pragma unroll
        for (int k = 0; k < 16; ++k) {
            y[(b*64 + 4*k)*1001 + t]     = yv4[k].x;
            y[(b*64 + 4*k + 1)*1001 + t] = yv4[k].y;
            y[(b*64 + 4*k + 2)*1001 + t] = yv4[k].z;
            y[(b*64 + 4*k + 3)*1001 + t] = yv4[k].w;
        }
    }

    for (int off = 32; off > 0; off >>= 1) hsq += __shfl_down(hsq, off, 64);
    int wid = tid >> 6, lane = tid & 63;
    if (lane == 0) wred[wid] = hsq;
    __syncthreads();
    if (tid == 0) hpart[blockIdx.x] = wred[0] + wred[1] + wred[2] + wred[3];
}

// ---------------------------------------------------------------------------
union SMu {
    float ytT[128][68];   // syrk staging, transposed (34816 B)
    float G[64][68];      // G[k][i] = element i of column k (17408 B)
};

__global__ __launch_bounds__(256) void k_eig(
    const float* __restrict__ y, const float* __restrict__ hpart,
    const float* __restrict__ fcw, const float* __restrict__ fcb,
    float* __restrict__ out)
{
    const int b    = blockIdx.x;
    const int tid  = threadIdx.x;
    const int w    = tid >> 6;     // wave 0..3
    const int lane = tid & 63;

    __shared__ SMu U;
    __shared__ float pgam[2][4][64];   // per-wave gamma partials, dbuf
    __shared__ float le[64];
    __shared__ float wred2[16];

    // ---- syrk: acc = y y^T; transposed staging, b128 MAC, 256 thr ----
    const int mg = tid >> 4, ng = tid & 15;
    const int m0 = mg * 4,  n0 = ng * 4;
    float acc[16];
    #pragma unroll
    for (int i = 0; i < 16; ++i) acc[i] = 0.f;
    for (int tile = 0; tile < 8; ++tile) {
        #pragma unroll
        for (int k = 0; k < 32; ++k) {
            int idx = tid + k*256;
            int col = idx >> 7, row = idx & 127;   // col=m, row=t-in-tile
            int tg = tile * 128 + row;
            U.ytT[row][col] = (tg <= 1000) ? y[(b*64 + col)*1001 + tg] : 0.f;
        }
        __syncthreads();
        for (int tt = 0; tt < 128; ++tt) {
            v4f ym = *(const v4f*)&U.ytT[tt][m0];
            v4f yn = *(const v4f*)&U.ytT[tt][n0];
            #pragma unroll
            for (int i = 0; i < 4; ++i)
                #pragma unroll
                for (int j = 0; j < 4; ++j) acc[i*4 + j] += ym[i] * yn[j];
        }
        __syncthreads();
    }
    {
        float hs = hpart[b*4] + hpart[b*4+1] + hpart[b*4+2] + hpart[b*4+3];
        float mu = hs / (999.f * 450.f);
        #pragma unroll
        for (int i = 0; i < 4; ++i)
            #pragma unroll
            for (int j = 0; j < 4; ++j) {
                int mm = m0 + i, nn = n0 + j;
                U.G[mm][nn] = acc[i*4 + j] * (0.95f / 999.f)
                            + ((mm == nn) ? 0.05f * mu : 0.f);
            }
    }
    __syncthreads();

    // ---- one-sided cyclic Jacobi, 4-wave row-split ----
    // Wave w, lane L: g[i] = G[L][16w+i], i=0..15.  Round rr pairs as before:
    //   partner(L) = rr if L==63; 63 if L==rr; else (2rr-L) mod 63;
    //   role p (sgn=+1) iff L==63 or 1 <= (L-rr) mod 63 <= 31.
    // gamma: per-wave 16-FMA partial (bitwise-identical on both lanes of a
    // pair), summed across waves via LDS in fixed order -> identical on all
    // participants.  Norms tracked redundantly per wave (identical updates).
    // Rotation branchless: g' = c*g + se*gq, se = -sgn*s.
    {
        const int r0 = 16 * w;
        float g[16];
        #pragma unroll
        for (int i = 0; i < 4; ++i) {
            v4f t4 = *(const v4f*)&U.G[lane][r0 + 4*i];
            g[4*i] = t4.x; g[4*i+1] = t4.y; g[4*i+2] = t4.z; g[4*i+3] = t4.w;
        }
        // initial column norms: cross-wave reduce of row-partials
        {
            float s0 = 0.f, s1 = 0.f, s2 = 0.f, s3 = 0.f;
            #pragma unroll
            for (int i = 0; i < 16; i += 4) {
                s0 += g[i]*g[i];     s1 += g[i+1]*g[i+1];
                s2 += g[i+2]*g[i+2]; s3 += g[i+3]*g[i+3];
            }
            pgam[0][w][lane] = (s0 + s1) + (s2 + s3);
        }
        __syncthreads();
        float nr = ((pgam[0][0][lane] + pgam[0][1][lane])
                 +  (pgam[0][2][lane] + pgam[0][3][lane]));
        __syncthreads();   // protect pgam[0] before round 0 rewrites it

        int par = 0;
        for (int sweep = 0; sweep < MAXSWEEP; ++sweep) {
            int allc = 1;
            for (int rr = 0; rr < 63; ++rr) {
                int partner, sgn;
                if (lane == 63) { partner = rr; sgn = 1; }
                else {
                    int d = lane - rr; if (d < 0) d += 63;
                    if (d == 0) { partner = 63; sgn = -1; }
                    else {
                        int pp = 2*rr - lane;
                        if (pp < 0)   pp += 63;
                        if (pp < 0)   pp += 63;
                        if (pp >= 63) pp -= 63;
                        partner = pp;
                        sgn = (d <= 31) ? 1 : -1;
                    }
                }
                float gq[16];
                #pragma unroll
                for (int i = 0; i < 16; ++i) gq[i] = __shfl(g[i], partner, 64);
                float nq = __shfl(nr, partner, 64);

                float s0 = 0.f, s1 = 0.f, s2 = 0.f, s3 = 0.f;
                #pragma unroll
                for (int i = 0; i < 16; i += 4) {
                    s0 += g[i]*gq[i];     s1 += g[i+1]*gq[i+1];
                    s2 += g[i+2]*gq[i+2]; s3 += g[i+3]*gq[i+3];
                }
                pgam[par][w][lane] = (s0 + s1) + (s2 + s3);
                __syncthreads();
                float gam = ((pgam[par][0][lane] + pgam[par][1][lane])
                          +  (pgam[par][2][lane] + pgam[par][3][lane]));
                par ^= 1;   // next round writes the other buffer (no 2nd barrier)

                if (fabsf(gam) > JTOL * sqrtf(nr * nq)) {
                    allc = 0;
                    float diff = (sgn > 0) ? (nq - nr) : (nr - nq);  // be - al
                    float tau = diff * __builtin_amdgcn_rcpf(2.f * gam);
                    float t  = copysignf(1.f, tau) / (fabsf(tau) + sqrtf(1.f + tau*tau));
                    float c  = rsqrtf(1.f + t*t);
                    float s  = t * c;
                    float se = (sgn > 0) ? -s : s;
                    #pragma unroll
                    for (int i = 0; i < 16; ++i) g[i] = c*g[i] + se*gq[i];
                    nr -= (sgn > 0) ? t*gam : -t*gam;
                }
            }
            if (__all(allc)) break;   // identical decision in all waves
        }

        // write back rows; fresh full norm -> le[k] = log(lambda)/lambda^2
        #pragma unroll
        for (int i = 0; i < 4; ++i) {
            v4f t4 = (v4f){g[4*i], g[4*i+1], g[4*i+2], g[4*i+3]};
            *(v4f*)&U.G[lane][r0 + 4*i] = t4;
        }
        {
            float s0 = 0.f, s1 = 0.f, s2 = 0.f, s3 = 0.f;
            #pragma unroll
            for (int i = 0; i < 16; i += 4) {
                s0 += g[i]*g[i];     s1 += g[i+1]*g[i+1];
                s2 += g[i+2]*g[i+2]; s3 += g[i+3]*g[i+3];
            }
            pgam[par][w][lane] = (s0 + s1) + (s2 + s3);
        }
        __syncthreads();
        if (w == 0) {
            float n2 = ((pgam[par][0][lane] + pgam[par][1][lane])
                     +  (pgam[par][2][lane] + pgam[par][3][lane]));
            n2 = fmaxf(n2, 1e-12f);
            le[lane] = 0.5f * logf(n2) / n2;   // log(sqrt(n2)) / n2
        }
    }
    __syncthreads();

    // ---- log-eig reconstruction + FC ----
    // log_mapped = sum_k le[k] * g_k g_k^T   (g_k = col k of G, contiguous)
    {
        float lm[16];
        #pragma unroll
        for (int i = 0; i < 16; ++i) lm[i] = 0.f;
        for (int k = 0; k < 64; ++k) {
            float l = le[k];
            v4f gm = *(const v4f*)&U.G[k][m0];
            v4f gn = *(const v4f*)&U.G[k][n0];
            #pragma unroll
            for (int i = 0; i < 4; ++i) {
                float vm = gm[i] * l;
                #pragma unroll
                for (int j = 0; j < 4; ++j) lm[i*4 + j] += vm * gn[j];
            }
        }

        float fa[4];
        #pragma unroll
        for (int o = 0; o < 4; ++o) fa[o] = 0.f;
        #pragma unroll
        for (int i = 0; i < 4; ++i)
            #pragma unroll
            for (int j = 0; j < 4; ++j) {
                int gi = m0 + i, gj = n0 + j;
                if (gi <= gj) {
                    int p = gi*64 - (gi*(gi-1))/2 + (gj - gi);
                    float lv = lm[i*4 + j];
                    #pragma unroll
                    for (int o = 0; o < 4; ++o) fa[o] += lv * fcw[o*2080 + p];
                }
            }

        #pragma unroll
        for (int o = 0; o < 4; ++o)
            for (int off = 32; off > 0; off >>= 1)
                fa[o] += __shfl_down(fa[o], off, 64);
        if (lane == 0) {
            #pragma unroll
            for (int o = 0; o < 4; ++o) wred2[w*4 + o] = fa[o];
        }
    }
    __syncthreads();
    if (tid < 4)
        out[b*4 + tid] = wred2[tid] + wred2[4 + tid] + wred2[8 + tid]
                       + wred2[12 + tid] + fcb[tid];
}

// ---------------------------------------------------------------------------
extern "C" void kernel_launch(void* const* d_in, const int* in_sizes, int n_in,
                              void* d_out, int out_size, void* d_ws, size_t ws_size,
                              hipStream_t stream) {
    (void)in_sizes; (void)n_in; (void)out_size; (void)ws_size;
    const float* x   = (const float*)d_in[0];
    const float* ws0 = (const float*)d_in[1];
    const float* ws1 = (const float*)d_in[2];
    const float* ws2 = (const float*)d_in[3];
    const float* bsg = (const float*)d_in[4];
    const float* bsb = (const float*)d_in[5];
    const float* bsm = (const float*)d_in[6];
    const float* bsv = (const float*)d_in[7];
    const float* wf  = (const float*)d_in[8];
    const float* bfg = (const float*)d_in[9];
    const float* bfb = (const float*)d_in[10];
    const float* bfm = (const float*)d_in[11];
    const float* bfv = (const float*)d_in[12];
    const float* wt0 = (const float*)d_in[13];
    const float* wt1 = (const float*)d_in[14];
    const float* wt2 = (const float*)d_in[15];
    const float* btg = (const float*)d_in[16];
    const float* btb = (const float*)d_in[17];
    const float* btm = (const float*)d_in[18];
    const float* btv = (const float*)d_in[19];
    const float* Wm  = (const float*)d_in[20];
    const float* fcw = (const float*)d_in[21];
    const float* fcb = (const float*)d_in[22];

    float* wsf   = (float*)d_ws;
    float* yb    = wsf + WS_Y;
    float* hpart = wsf + WS_HPART;

    k_prep<<<1, 512, 0, stream>>>(ws0, ws1, ws2, bsg, bsb, bsm, bsv,
                                  wf, bfg, bfb, bfm, bfv,
                                  wt0, wt1, wt2, btg, btb, btm, btv, wsf);
    k_main<<<512, 256, 0, stream>>>(x, wsf, Wm, yb, hpart);
    k_eig<<<128, 256, 0, stream>>>(yb, hpart, fcw, fcb, (float*)d_out);
}